// Round 7
// baseline (530.070 us; speedup 1.0000x reference)
//
#include <hip/hip_runtime.h>
#include <cstdint>
#include <cstddef>

// ---------------------------------------------------------------------------
// Types / helpers
// ---------------------------------------------------------------------------
typedef __bf16 bf16x8 __attribute__((ext_vector_type(8)));
typedef __bf16 bf16x4 __attribute__((ext_vector_type(4)));
typedef float  floatx4 __attribute__((ext_vector_type(4)));

__device__ __forceinline__ uint16_t f2b(float f) {
    uint32_t u = __builtin_bit_cast(uint32_t, f);
    return (uint16_t)((u + 0x7fffu + ((u >> 16) & 1)) >> 16);  // RNE
}

__device__ __forceinline__ uint16_t bf16bits(float f) {       // HW v_cvt (RNE)
    __bf16 h = (__bf16)f;
    return __builtin_bit_cast(uint16_t, h);
}

__device__ __forceinline__ void gload_lds16(const void* g, void* l) {
    __builtin_amdgcn_global_load_lds(
        (__attribute__((address_space(1))) void*)(void*)g,
        (__attribute__((address_space(3))) void*)l, 16, 0, 0);
}

// DPP row_ror helpers: 16-lane-row reductions entirely in the VALU pipe.
template<int CTRL>
__device__ __forceinline__ float dpp_rot(float v) {
    return __builtin_bit_cast(float,
        __builtin_amdgcn_update_dpp(0, __builtin_bit_cast(int, v),
                                    CTRL, 0xf, 0xf, true));
}
__device__ __forceinline__ float rowmax16(float v) {
    v = fmaxf(v, dpp_rot<0x128>(v));
    v = fmaxf(v, dpp_rot<0x124>(v));
    v = fmaxf(v, dpp_rot<0x122>(v));
    v = fmaxf(v, dpp_rot<0x121>(v));
    return v;
}
__device__ __forceinline__ float rowsum16(float v) {
    v += dpp_rot<0x128>(v);
    v += dpp_rot<0x124>(v);
    v += dpp_rot<0x122>(v);
    v += dpp_rot<0x121>(v);
    return v;
}

// 0.125 (1/sqrt(HD)) * log2(e): folded into Wq/bq so softmax is exp2-domain.
#define QSCALE 0.18033688011112042f

// ---------------------------------------------------------------------------
// Weight repack kernels (fp32 -> bf16, transposed to [N][K])
// ---------------------------------------------------------------------------
__global__ __launch_bounds__(256) void repack_qkv(
    const float* __restrict__ Wq, const float* __restrict__ Wk,
    const float* __restrict__ Wv, uint16_t* __restrict__ out)
{
    __shared__ uint16_t tile[32][33];
    const int m = blockIdx.z >> 4, h = blockIdx.z & 15;
    const float* W = (m == 0) ? Wq : (m == 1) ? Wk : Wv;
    const float scl = (m == 0) ? QSCALE : 1.0f;
    const float* src = W + (size_t)h * 1024 * 64;           // [1024][64]
    const int d0 = blockIdx.x * 32, hd0 = blockIdx.y * 32;
    const int tx = threadIdx.x & 31, ty = threadIdx.x >> 5;
#pragma unroll
    for (int i = 0; i < 4; ++i)
        tile[ty + i * 8][tx] = f2b(src[(size_t)(d0 + ty + i * 8) * 64 + hd0 + tx] * scl);
    __syncthreads();
    uint16_t* dst = out + (size_t)(m * 1024 + h * 64) * 1024; // [64][1024]
#pragma unroll
    for (int i = 0; i < 4; ++i)
        dst[(size_t)(hd0 + ty + i * 8) * 1024 + d0 + tx] = tile[tx][ty + i * 8];
}

__global__ __launch_bounds__(256) void transpose_f2b(
    const float* __restrict__ in, uint16_t* __restrict__ out, int R, int C)
{
    __shared__ uint16_t tile[32][33];
    const int c0 = blockIdx.x * 32, r0 = blockIdx.y * 32;
    const int tx = threadIdx.x & 31, ty = threadIdx.x >> 5;
#pragma unroll
    for (int i = 0; i < 4; ++i)
        tile[ty + i * 8][tx] = f2b(in[(size_t)(r0 + ty + i * 8) * C + c0 + tx]);
    __syncthreads();
#pragma unroll
    for (int i = 0; i < 4; ++i)
        out[(size_t)(c0 + ty + i * 8) * R + r0 + tx] = tile[tx][ty + i * 8];
}

__global__ void concat_bias(const float* __restrict__ bq, const float* __restrict__ bk,
                            const float* __restrict__ bv, float* __restrict__ out)
{
    int i = blockIdx.x * 256 + threadIdx.x;  // 3072 total
    out[i] = (i < 1024) ? bq[i] * QSCALE : (i < 2048) ? bk[i - 1024] : bv[i - 2048];
}

// V slice of qkv [B*T][3072] -> Vt [(b*16+h)*64+hd][2048], with the key axis
// PERMUTED within each 64-key block: stored s = (key&15)*4 + (key>>4)&3.
// This matches the packed P-store k-order in attn (MFMA k-permutation applied
// consistently to both PV operands -> exact).
__global__ __launch_bounds__(256) void transpose_v(
    const uint16_t* __restrict__ qkv, uint16_t* __restrict__ Vt)
{
    __shared__ uint16_t tile[32][33];
    const int bh = blockIdx.z;
    const int b = bh >> 4, h = bh & 15;
    const int t0 = blockIdx.x * 32, hd0 = blockIdx.y * 32;
    const int tx = threadIdx.x & 31, ty = threadIdx.x >> 5;
    const uint16_t* src = qkv + (size_t)b * 2048 * 3072 + 2048 + h * 64;
#pragma unroll
    for (int i = 0; i < 4; ++i)
        tile[ty + i * 8][tx] = src[(size_t)(t0 + ty + i * 8) * 3072 + hd0 + tx];
    __syncthreads();
    uint16_t* dst = Vt + (size_t)bh * 64 * 2048;
    const int key = t0 + tx;
    const int kp  = (key & ~63) | (((key & 15) << 2) | ((key >> 4) & 3));
#pragma unroll
    for (int i = 0; i < 4; ++i)
        dst[(size_t)(hd0 + ty + i * 8) * 2048 + kp] = tile[tx][ty + i * 8];
}

// ---------------------------------------------------------------------------
// LayerNorm: fp32 [rows][1024] -> bf16, one block per row
// ---------------------------------------------------------------------------
__global__ __launch_bounds__(256) void ln_bf16(
    const float* __restrict__ x, const float* __restrict__ g,
    const float* __restrict__ b, uint16_t* __restrict__ out)
{
    const int row = blockIdx.x;
    const int t = threadIdx.x;
    const float4 v = ((const float4*)(x + (size_t)row * 1024))[t];
    float s  = v.x + v.y + v.z + v.w;
    float s2 = v.x * v.x + v.y * v.y + v.z * v.z + v.w * v.w;
#pragma unroll
    for (int o = 32; o > 0; o >>= 1) { s += __shfl_down(s, o); s2 += __shfl_down(s2, o); }
    __shared__ float red[8];
    const int wave = t >> 6, lane = t & 63;
    if (lane == 0) { red[wave] = s; red[4 + wave] = s2; }
    __syncthreads();
    if (t == 0) {
        float a  = red[0] + red[1] + red[2] + red[3];
        float a2 = red[4] + red[5] + red[6] + red[7];
        float mu = a * (1.0f / 1024.0f);
        red[0] = mu;
        red[4] = rsqrtf(a2 * (1.0f / 1024.0f) - mu * mu + 1e-5f);
    }
    __syncthreads();
    const float mu = red[0], rs = red[4];
    const float4 gv = ((const float4*)g)[t];
    const float4 bv = ((const float4*)b)[t];
    ushort4 ov;
    ov.x = f2b((v.x - mu) * rs * gv.x + bv.x);
    ov.y = f2b((v.y - mu) * rs * gv.y + bv.y);
    ov.z = f2b((v.z - mu) * rs * gv.z + bv.z);
    ov.w = f2b((v.w - mu) * rs * gv.w + bv.w);
    ((ushort4*)(out + (size_t)row * 1024))[t] = ov;
}

// ---------------------------------------------------------------------------
// GEMM: C[M,N] = A[M,K](bf16,rowmajor) * Bt[N,K](bf16,rowmajor)^T + bias
// mode 0: out bf16            mode 1: out fp32 + resid      mode 2: bf16 gelu
// 128x128 tile, BK=64. XCD-aware banding. Conflict-free XOR-swizzled LDS.
// 3 blocks/CU. Requires: M % 1024 == 0, N % 1024 == 0, K % 64 == 0.
// ---------------------------------------------------------------------------
__global__ __launch_bounds__(256, 3) void gemm_bf16(
    const uint16_t* __restrict__ A, const uint16_t* __restrict__ Bt,
    int M, int N, int K,
    const float* __restrict__ bias, const float* __restrict__ resid,
    float* __restrict__ outF, uint16_t* __restrict__ outB, int mode)
{
    __shared__ __align__(16) uint16_t lds[128 * 128];   // 32KB: staging + epilogue
    uint16_t* lA = lds;                                  // 128x64 (16KB)
    uint16_t* lB = lds + 128 * 64;                       // 16KB
    const int tid  = threadIdx.x;
    const int wave = tid >> 6, lane = tid & 63;

    // XCD-aware tile mapping
    const int lid = (int)blockIdx.y * (int)gridDim.x + (int)blockIdx.x;
    const int xcd = lid & 7, t = lid >> 3;
    const int Mb = (M >> 7) >> 3;          // tile-rows per XCD band (pow2)
    const int perChunk = Mb * 8;
    const int ch = t / perChunk, j = t - ch * perChunk;
    const int m0 = (xcd * Mb + (j & (Mb - 1))) * 128;
    const int n0 = (ch * 8 + (j / Mb)) * 128;

    const int wm = (wave >> 1) * 64, wn = (wave & 1) * 64;
    const int quad = lane >> 4, lrow = lane & 15;
    const int wbase = wave * 64;

    floatx4 acc[4][4] = {};

    const uint16_t* aT = A  + (size_t)m0 * K;
    const uint16_t* bT = Bt + (size_t)n0 * K;

    for (int k0 = 0; k0 < K; k0 += 64) {
        __syncthreads();
#pragma unroll
        for (int i = 0; i < 4; ++i) {
            const int cw = i * 256 + wbase;      // wave-uniform chunk base
            const int q  = cw + lane;            // LDS slot chunk id (0..1023)
            const int row = q >> 3;
            const int g = ((q & 7) ^ (row & 7)) * 8;   // swizzled global chunk
            gload_lds16(aT + (size_t)row * K + k0 + g, &lA[cw * 8]);
            gload_lds16(bT + (size_t)row * K + k0 + g, &lB[cw * 8]);
        }
        __syncthreads();
        bf16x8 af[4][2], bfr[4][2];
#pragma unroll
        for (int mi = 0; mi < 4; ++mi) {
            const int rr = wm + mi * 16 + lrow;
#pragma unroll
            for (int hh = 0; hh < 2; ++hh)
                af[mi][hh] = *(const bf16x8*)
                    &lA[rr * 64 + (((hh * 4 + quad) ^ (rr & 7)) * 8)];
        }
#pragma unroll
        for (int ni = 0; ni < 4; ++ni) {
            const int rr = wn + ni * 16 + lrow;
#pragma unroll
            for (int hh = 0; hh < 2; ++hh)
                bfr[ni][hh] = *(const bf16x8*)
                    &lB[rr * 64 + (((hh * 4 + quad) ^ (rr & 7)) * 8)];
        }
#pragma unroll
        for (int mi = 0; mi < 4; ++mi)
#pragma unroll
            for (int ni = 0; ni < 4; ++ni) {
                acc[mi][ni] = __builtin_amdgcn_mfma_f32_16x16x32_bf16(
                    af[mi][0], bfr[ni][0], acc[mi][ni], 0, 0, 0);
                acc[mi][ni] = __builtin_amdgcn_mfma_f32_16x16x32_bf16(
                    af[mi][1], bfr[ni][1], acc[mi][ni], 0, 0, 0);
            }
    }

    __syncthreads();                           // staging buffers free now
    const int r0 = (lane >> 4) * 4;

    if (mode == 1) {
        // fp32 + residual, two 64-row passes staged in LDS (32KB fp32)
        float* cf = (float*)lds;
#pragma unroll
        for (int p = 0; p < 2; ++p) {
            if ((wave >> 1) == p) {
#pragma unroll
                for (int ni = 0; ni < 4; ++ni) {
                    const int col = wn + ni * 16 + lrow;
                    const float bv = bias[n0 + col];
#pragma unroll
                    for (int mi = 0; mi < 4; ++mi)
#pragma unroll
                        for (int r = 0; r < 4; ++r) {
                            const int row = mi * 16 + r0 + r;       // 0..63
                            const int g = (col >> 2) ^ (((row >> 2) & 1) << 2);
                            cf[row * 128 + g * 4 + (col & 3)] = acc[mi][ni][r] + bv;
                        }
                }
            }
            __syncthreads();
#pragma unroll
            for (int i = 0; i < 8; ++i) {
                const int ci = i * 256 + tid;        // 16B chunk id
                const int row = ci >> 5, cg = ci & 31;
                const int g = cg ^ (((row >> 2) & 1) << 2);
                float4 v = *(const float4*)&cf[row * 128 + g * 4];
                const size_t gidx = (size_t)(m0 + p * 64 + row) * N + n0 + cg * 4;
                const float4 rz = *(const float4*)&resid[gidx];
                v.x += rz.x; v.y += rz.y; v.z += rz.z; v.w += rz.w;
                *(float4*)&outF[gidx] = v;
            }
            __syncthreads();
        }
    } else {
        // bf16 out (mode 0 plain / mode 2 gelu), full 128x128 tile in LDS
#pragma unroll
        for (int ni = 0; ni < 4; ++ni) {
            const int col = wn + ni * 16 + lrow;
            const float bv = bias[n0 + col];
#pragma unroll
            for (int mi = 0; mi < 4; ++mi)
#pragma unroll
                for (int r = 0; r < 4; ++r) {
                    const int row = wm + mi * 16 + r0 + r;
                    float v = acc[mi][ni][r] + bv;
                    if (mode == 2)
                        v = 0.5f * v * (1.0f + erff(v * 0.70710678118654752f));
                    const int g = (col >> 3) ^ (((row >> 2) & 3) << 1);
                    lds[row * 128 + g * 8 + (col & 7)] = bf16bits(v);
                }
        }
        __syncthreads();
#pragma unroll
        for (int i = 0; i < 8; ++i) {
            const int ci = i * 256 + tid;            // 16B chunk id
            const int row = ci >> 4, cg = ci & 15;
            const int g = cg ^ (((row >> 2) & 3) << 1);
            const bf16x8 v = *(const bf16x8*)&lds[row * 128 + g * 8];
            *(bf16x8*)&outB[(size_t)(m0 + row) * N + n0 + cg * 8] = v;
        }
    }
}

// ---------------------------------------------------------------------------
// Flash attention v5 (causal, fused q-pair, 2 blocks/CU).
// Grid (8, 16, 4): block x owns q-tiles A=15-x (heavy) and B=x (light), 128
// rows each, processed in ONE pass over K-tiles sharing staged K/V (200
// tile-stages per (b,h) vs 272 split) -> fewer barriers + less refetch.
// Packed P-store: P k-order permuted (stored s = lcol*4+nt, key=(s&3)*16+
// (s>>2)); Vt pre-permuted identically -> one ds_write_b64 per 4 scores.
// Softmax exp2-domain; DPP reductions; vectorized (pk) alpha rescale.
// ---------------------------------------------------------------------------
__global__ __launch_bounds__(256, 2) void attn_kernel(
    const uint16_t* __restrict__ qkv, const uint16_t* __restrict__ Vt,
    uint16_t* __restrict__ ctx)
{
    const int h = blockIdx.y, b = blockIdx.z;
    const int tid = threadIdx.x, wave = tid >> 6, lane = tid & 63;
    const int quad = lane >> 4, lcol = lane & 15, lr4 = quad * 4;
    const int sx = lcol & 7;
    const uint16_t* qbase = qkv + (size_t)b * 2048 * 3072;
    const uint16_t* kgb = qbase + 1024 + h * 64;
    const uint16_t* vtb = Vt + (size_t)(b * 16 + h) * 64 * 2048;

    __shared__ __align__(16) uint16_t kbuf[2][64 * 64];
    __shared__ __align__(16) uint16_t vbuf[2][64 * 64];
    __shared__ __align__(16) uint16_t pshm[4][32 * 64];
    uint16_t* psw = &pshm[wave][0];

    const int rr = lane >> 3, sl = lane & 7;
    const int swz = sl ^ rr;                 // global 16B-chunk this lane fetches

#define STAGE(ktile, bb)                                                        \
    {                                                                           \
        const int _kb = (ktile) * 64;                                           \
        _Pragma("unroll")                                                       \
        for (int i = 0; i < 2; ++i) {                                           \
            const int j = wave * 2 + i;                                         \
            const int r = j * 8 + rr;                                           \
            gload_lds16(kgb + (size_t)(_kb + r) * 3072 + swz * 8,               \
                        &kbuf[bb][j * 512]);                                    \
            gload_lds16(vtb + (size_t)r * 2048 + _kb + swz * 8,                 \
                        &vbuf[bb][j * 512]);                                    \
        }                                                                       \
    }

    const int qtA = 15 - (int)blockIdx.x, qtB = (int)blockIdx.x;
    const int qr0A = qtA * 128 + wave * 32;
    const int qr0B = qtB * 128 + wave * 32;

    // Q fragments (A-layout): m = lcol, k = quad*8+j (+32 second chunk)
    bf16x8 qfA[2][2], qfB[2][2];
#pragma unroll
    for (int mi = 0; mi < 2; ++mi) {
        const uint16_t* qpA = qbase + (size_t)(qr0A + mi * 16 + lcol) * 3072 + h * 64;
        qfA[mi][0] = *(const bf16x8*)(qpA + quad * 8);
        qfA[mi][1] = *(const bf16x8*)(qpA + 32 + quad * 8);
        const uint16_t* qpB = qbase + (size_t)(qr0B + mi * 16 + lcol) * 3072 + h * 64;
        qfB[mi][0] = *(const bf16x8*)(qpB + quad * 8);
        qfB[mi][1] = *(const bf16x8*)(qpB + 32 + quad * 8);
    }

    floatx4 oA[2][4] = {}, oB[2][4] = {};
    float mA[2][4], lA_[2][4], mB[2][4], lB_[2][4];
#pragma unroll
    for (int mi = 0; mi < 2; ++mi)
#pragma unroll
        for (int r = 0; r < 4; ++r) {
            mA[mi][r] = -1e30f; lA_[mi][r] = 0.f;
            mB[mi][r] = -1e30f; lB_[mi][r] = 0.f;
        }

    const int nk = 2 * qtA + 2;
    STAGE(0, 0);
    int cur = 0;

    for (int kt = 0; kt < nk; ++kt) {
        const int kb = kt * 64;
        __syncthreads();                   // drains vmcnt: buf[cur] ready
        if (kt + 1 < nk) STAGE(kt + 1, cur ^ 1);

        // K fragments shared by both q-tiles
        bf16x8 kf[4][2];
#pragma unroll
        for (int nt = 0; nt < 4; ++nt) {
            const int krow = nt * 16 + lcol;
            kf[nt][0] = *(const bf16x8*)&kbuf[cur][krow * 64 + ((quad ^ sx) * 8)];
            kf[nt][1] = *(const bf16x8*)&kbuf[cur][krow * 64 + (((quad + 4) ^ sx) * 8)];
        }

        auto process = [&](const bf16x8 (&qf)[2][2], floatx4 (&o)[2][4],
                           float (&m_i)[2][4], float (&l_i)[2][4], const int qr0) {
#pragma unroll
            for (int mi = 0; mi < 2; ++mi) {
                floatx4 sv[4];
#pragma unroll
                for (int nt = 0; nt < 4; ++nt) {
                    floatx4 s = {0.f, 0.f, 0.f, 0.f};
                    s = __builtin_amdgcn_mfma_f32_16x16x32_bf16(qf[mi][0], kf[nt][0], s, 0, 0, 0);
                    s = __builtin_amdgcn_mfma_f32_16x16x32_bf16(qf[mi][1], kf[nt][1], s, 0, 0, 0);
                    sv[nt] = s;
                }
                if (kb + 63 > qr0 + mi * 16) {     // causal mask needed
#pragma unroll
                    for (int nt = 0; nt < 4; ++nt)
#pragma unroll
                        for (int r = 0; r < 4; ++r) {
                            const int row = qr0 + mi * 16 + lr4 + r;
                            const int col = kb + nt * 16 + lcol;
                            if (col > row) sv[nt][r] = -1e30f;
                        }
                }
                floatx4 alphav;
#pragma unroll
                for (int r = 0; r < 4; ++r) {
                    float m = fmaxf(fmaxf(sv[0][r], sv[1][r]),
                                    fmaxf(sv[2][r], sv[3][r]));
                    m = rowmax16(m);
                    const float mn = fmaxf(m_i[mi][r], m);
                    const float alpha = __builtin_amdgcn_exp2f(m_i[mi][r] - mn);
                    m_i[mi][r] = mn;
                    const float p0 = __builtin_amdgcn_exp2f(sv[0][r] - mn);
                    const float p1 = __builtin_amdgcn_exp2f(sv[1][r] - mn);
                    const float p2 = __builtin_amdgcn_exp2f(sv[2][r] - mn);
                    const float p3 = __builtin_amdgcn_exp2f(sv[3][r] - mn);
                    float l = p0 + p1 + p2 + p3;
                    l = rowsum16(l);
                    l_i[mi][r] = l_i[mi][r] * alpha + l;
                    alphav[r] = alpha;
                    // packed P-store: stored s = lcol*4 + nt (permuted k-order)
                    const int row = mi * 16 + lr4 + r;
                    bf16x4 pk4;
                    pk4[0] = (__bf16)p0; pk4[1] = (__bf16)p1;
                    pk4[2] = (__bf16)p2; pk4[3] = (__bf16)p3;
                    const int chunk = (lcol >> 1) ^ (row & 7);
                    *(bf16x4*)&psw[row * 64 + chunk * 8 + (lcol & 1) * 4] = pk4;
                }
#pragma unroll
                for (int ht = 0; ht < 4; ++ht) o[mi][ht] *= alphav;
            }
            // P (A-layout, permuted k) from pshm; V (permuted k) from vbuf
            bf16x8 pf[2][2];
#pragma unroll
            for (int mi = 0; mi < 2; ++mi) {
                const int prow = mi * 16 + lcol;
                pf[mi][0] = *(const bf16x8*)&psw[prow * 64 + ((quad ^ sx) * 8)];
                pf[mi][1] = *(const bf16x8*)&psw[prow * 64 + (((quad + 4) ^ sx) * 8)];
            }
#pragma unroll
            for (int ht = 0; ht < 4; ++ht) {
                const int hd = ht * 16 + lcol;
                const bf16x8 vf0 = *(const bf16x8*)&vbuf[cur][hd * 64 + ((quad ^ sx) * 8)];
                const bf16x8 vf1 = *(const bf16x8*)&vbuf[cur][hd * 64 + (((quad + 4) ^ sx) * 8)];
#pragma unroll
                for (int mi = 0; mi < 2; ++mi) {
                    o[mi][ht] = __builtin_amdgcn_mfma_f32_16x16x32_bf16(pf[mi][0], vf0, o[mi][ht], 0, 0, 0);
                    o[mi][ht] = __builtin_amdgcn_mfma_f32_16x16x32_bf16(pf[mi][1], vf1, o[mi][ht], 0, 0, 0);
                }
            }
        };

        if (kb <= qr0A + 31) process(qfA, oA, mA, lA_, qr0A);
        if (kb <= qr0B + 31) process(qfB, oB, mB, lB_, qr0B);
        cur ^= 1;
    }
#undef STAGE

#pragma unroll
    for (int mi = 0; mi < 2; ++mi)
#pragma unroll
        for (int r = 0; r < 4; ++r) {
            const float invA = 1.0f / lA_[mi][r];
            const float invB = 1.0f / lB_[mi][r];
            const int rowA = qr0A + mi * 16 + lr4 + r;
            const int rowB = qr0B + mi * 16 + lr4 + r;
#pragma unroll
            for (int ht = 0; ht < 4; ++ht) {
                ctx[(size_t)(b * 2048 + rowA) * 1024 + h * 64 + ht * 16 + lcol] =
                    bf16bits(oA[mi][ht][r] * invA);
                ctx[(size_t)(b * 2048 + rowB) * 1024 + h * 64 + ht * 16 + lcol] =
                    bf16bits(oB[mi][ht][r] * invB);
            }
        }
}

// ---------------------------------------------------------------------------
// Launch
// ---------------------------------------------------------------------------
extern "C" void kernel_launch(void* const* d_in, const int* in_sizes, int n_in,
                              void* d_out, int out_size, void* d_ws, size_t ws_size,
                              hipStream_t stream)
{
    (void)in_sizes; (void)n_in; (void)out_size; (void)ws_size;
    const float* x     = (const float*)d_in[0];
    const float* ln1_g = (const float*)d_in[2];
    const float* ln1_b = (const float*)d_in[3];
    const float* Wq    = (const float*)d_in[4];
    const float* bq    = (const float*)d_in[5];
    const float* Wk    = (const float*)d_in[6];
    const float* bk    = (const float*)d_in[7];
    const float* Wv    = (const float*)d_in[8];
    const float* bv    = (const float*)d_in[9];
    const float* Wo    = (const float*)d_in[10];
    const float* bo    = (const float*)d_in[11];
    const float* ln2_g = (const float*)d_in[12];
    const float* ln2_b = (const float*)d_in[13];
    const float* W1    = (const float*)d_in[14];
    const float* b1    = (const float*)d_in[15];
    const float* W2    = (const float*)d_in[16];
    const float* b2    = (const float*)d_in[17];
    float* out = (float*)d_out;

    char* w = (char*)d_ws;
    uint16_t* Wqkv_t = (uint16_t*)w;  w += 6291456;    // [3072][1024]
    uint16_t* Wo_t   = (uint16_t*)w;  w += 2097152;    // [1024][1024]
    uint16_t* W1_t   = (uint16_t*)w;  w += 8388608;    // [4096][1024]
    uint16_t* W2_t   = (uint16_t*)w;  w += 8388608;    // [1024][4096]
    float*    bqkv   = (float*)w;     w += 16384;      // [3072]
    float*    x2     = (float*)w;     w += 33554432;   // [8192][1024] fp32
    char* region = w;
    uint16_t* hbuf = (uint16_t*)region;                        // 16MB h, later ctx
    uint16_t* qkv  = (uint16_t*)(region + 16777216);           // 48MB
    uint16_t* Vt   = (uint16_t*)(region + 16777216 + 50331648);// 16MB
    uint16_t* ctx  = hbuf;
    uint16_t* h2   = (uint16_t*)region;
    uint16_t* a1   = (uint16_t*)(region + 16777216);

    repack_qkv<<<dim3(32, 2, 48), 256, 0, stream>>>(Wq, Wk, Wv, Wqkv_t);
    transpose_f2b<<<dim3(32, 32),  256, 0, stream>>>(Wo, Wo_t, 1024, 1024);
    transpose_f2b<<<dim3(128, 32), 256, 0, stream>>>(W1, W1_t, 1024, 4096);
    transpose_f2b<<<dim3(32, 128), 256, 0, stream>>>(W2, W2_t, 4096, 1024);
    concat_bias<<<12, 256, 0, stream>>>(bq, bk, bv, bqkv);
    ln_bf16<<<8192, 256, 0, stream>>>(x, ln1_g, ln1_b, hbuf);
    gemm_bf16<<<dim3(24, 64), 256, 0, stream>>>(hbuf, Wqkv_t, 8192, 3072, 1024,
                                                bqkv, nullptr, nullptr, qkv, 0);
    transpose_v<<<dim3(64, 2, 64), 256, 0, stream>>>(qkv, Vt);
    attn_kernel<<<dim3(8, 16, 4), 256, 0, stream>>>(qkv, Vt, ctx);
    gemm_bf16<<<dim3(8, 64), 256, 0, stream>>>(ctx, Wo_t, 8192, 1024, 1024,
                                               bo, x, x2, nullptr, 1);
    ln_bf16<<<8192, 256, 0, stream>>>(x2, ln2_g, ln2_b, h2);
    gemm_bf16<<<dim3(32, 64), 256, 0, stream>>>(h2, W1_t, 8192, 4096, 1024,
                                                b1, nullptr, nullptr, a1, 2);
    gemm_bf16<<<dim3(8, 64), 256, 0, stream>>>(a1, W2_t, 8192, 1024, 4096,
                                               b2, x2, out, nullptr, 1);
}